// Round 16
// baseline (149.242 us; speedup 1.0000x reference)
//
#include <hip/hip_runtime.h>

#define BB 64
#define SS 2048
#define HH 512
#define MROWS (BB*SS)  // 131072

typedef __attribute__((ext_vector_type(8))) short short8;
typedef __attribute__((ext_vector_type(4))) float f32x4;

__device__ inline unsigned short f2bf(float f){
  unsigned int u = __float_as_uint(f);
  u += 0x7FFFu + ((u >> 16) & 1u);   // RNE
  return (unsigned short)(u >> 16);
}

// batch_lens may be int64 (reference) or int32. For int64 LE the high word of
// element 0 is 0 (lens in [1,2048]); for int32, p[1] is a len >= 1.
__device__ inline int read_len(const void* lens, int i){
  const int* p = (const int*)lens;
  if (p[1] == 0) return (int)((const long long*)lens)[i];
  return p[i];
}

__device__ inline float fast_tanh(float x){
  x = fminf(fmaxf(x, -15.f), 15.f);
  float e = __expf(2.f * x);
  return (e - 1.f) / (e + 1.f);
}

__device__ inline void gload16(const void* gptr, void* lptr){
  __builtin_amdgcn_global_load_lds(
      (const __attribute__((address_space(1))) void*)gptr,
      (__attribute__((address_space(3))) void*)lptr, 16, 0, 0);
}

__device__ inline short8 cvt8p(float4 x0, float4 x1){
  short8 r;
  r[0] = (short)f2bf(x0.x); r[1] = (short)f2bf(x0.y);
  r[2] = (short)f2bf(x0.z); r[3] = (short)f2bf(x0.w);
  r[4] = (short)f2bf(x1.x); r[5] = (short)f2bf(x1.y);
  r[6] = (short)f2bf(x1.z); r[7] = (short)f2bf(x1.w);
  return r;
}

// ---------- tiny pre-convert: W only (1 MB -> 512 KB bf16) ----------
__global__ __launch_bounds__(256) void convw_kernel(
    const float* __restrict__ W, unsigned short* __restrict__ Wb)
{
  size_t base = (size_t)blockIdx.x * 64 * HH;
  int t = threadIdx.x;
  #pragma unroll
  for (int j = 0; j < 32; j++) {
    size_t idx = base + (size_t)j * 1024 + t * 4;
    float4 v = *(const float4*)(W + idx);
    unsigned int p0 = (unsigned int)f2bf(v.x) | ((unsigned int)f2bf(v.y) << 16);
    unsigned int p1 = (unsigned int)f2bf(v.z) | ((unsigned int)f2bf(v.w) << 16);
    *(uint2*)(Wb + idx) = make_uint2(p0, p1);
  }
}

// ---------- pass 1: r4 geometry, 32 KB LDS -> 4 blocks/CU ----------
// BM=128, BN=128 (4 ntile-blocks/mtile), BK=64. 256 thr / 4 waves as 2M x 2N,
// wave tile 64x64, acc 4x4 = 64 VGPR. A reg-staged bf16 (16 KB), B via
// gload_lds (16 KB), both single-buffered. Cross-block overlap on the CU
// hides barrier drains (m114 mechanism) -- the lever r6-r15 lacked.
__global__ __launch_bounds__(256, 4) void scores4(
    const float* __restrict__ X, const unsigned short* __restrict__ Wb,
    const void* __restrict__ lens, const float* __restrict__ ctx,
    const float* __restrict__ pb, float* __restrict__ sp)
{
  int bid = blockIdx.x;
  int wg = (bid & 7) * 512 + (bid >> 3);   // XCD swizzle (4096 % 8 == 0)
  int ntile = wg & 3;
  int mtile = wg >> 2;
  int s_start = (mtile * 128) & (SS - 1);
  int b = (mtile * 128) >> 11;
  if (s_start >= read_len(lens, b)) return;

  __shared__ __align__(16) unsigned short As[128 * 64];   // 16 KB, swz
  __shared__ __align__(16) unsigned short Bs[128 * 64];   // 16 KB, swz

  int tid = threadIdx.x;
  int lane = tid & 63;
  int w = tid >> 6;            // 0..3
  int wm = w >> 1, wn = w & 1; // 2M x 2N, wave tile 64 x 64
  int l15 = lane & 15, g = lane >> 4;

  f32x4 acc[4][4];
  #pragma unroll
  for (int i = 0; i < 4; i++)
    #pragma unroll
    for (int j = 0; j < 4; j++) acc[i][j] = (f32x4)0.f;

  // ---- A reg-staging: thread t -> row t>>1, logical groups (t&1)*4 + j ----
  int arow = tid >> 1;
  int alg0 = (tid & 1) * 4;
  const float* Ag = X + (size_t)(mtile * 128 + arow) * HH + alg0 * 8;
  int apg[4];
  #pragma unroll
  for (int j = 0; j < 4; j++) apg[j] = (alg0 + j) ^ (arow & 7);

  // ---- B gload_lds: wave w stages rows [w*32, w*32+32); linear dest,
  // inverse-swizzled global source ----
  int brow = lane >> 3;
  int blg = (lane & 7) ^ brow;
  const unsigned short* Bg =
      Wb + (size_t)(ntile * 128 + w * 32 + brow) * HH + blg * 8;

  for (int t = 0; t < 8; ++t) {
    int kt = t * 64;
    // stage B (4 gloads/wave)
    #pragma unroll
    for (int i_ = 0; i_ < 4; i_++)
      gload16(Bg + (size_t)(i_ * 8) * HH + kt, &Bs[(w * 32 + i_ * 8) * 64]);
    // stage A: 8 float4 loads -> cvt -> 4 b128 writes
    {
      float4 ar[8];
      #pragma unroll
      for (int j = 0; j < 4; j++) {
        const float* p = Ag + kt + j * 8;
        ar[2 * j]     = *(const float4*)p;
        ar[2 * j + 1] = *(const float4*)(p + 4);
      }
      #pragma unroll
      for (int j = 0; j < 4; j++)
        *(short8*)&As[arow * 64 + apg[j] * 8] = cvt8p(ar[2 * j], ar[2 * j + 1]);
    }
    __syncthreads();                    // A writes + B gloads complete
    #pragma unroll
    for (int kk = 0; kk < 64; kk += 32) {
      int ga = g + (kk >> 3);
      short8 af[4], bq[4];
      #pragma unroll
      for (int im = 0; im < 4; im++) {
        int r = wm * 64 + im * 16 + l15;
        af[im] = *(const short8*)&As[r * 64 + ((ga ^ (r & 7))) * 8];
      }
      #pragma unroll
      for (int in = 0; in < 4; in++) {
        int r2 = wn * 64 + in * 16 + l15;
        bq[in] = *(const short8*)&Bs[r2 * 64 + ((ga ^ (r2 & 7))) * 8];
      }
      #pragma unroll
      for (int im = 0; im < 4; im++)
        #pragma unroll
        for (int in = 0; in < 4; in++)
          acc[im][in] = __builtin_amdgcn_mfma_f32_16x16x32_bf16(
              af[im], bq[in], acc[im][in], 0, 0, 0);
    }
    __syncthreads();                    // reads done before next overwrite
  }

  // Epilogue (r4-verbatim): tanh(P + pb)*ctx, reduce over this block's 128
  // cols -> per-row partial in plane (ntile*2 + wn).
  float pbv[4], ctxv[4];
  #pragma unroll
  for (int in = 0; in < 4; in++) {
    int a_g = ntile * 128 + wn * 64 + in * 16 + l15;
    pbv[in] = pb[a_g];
    ctxv[in] = ctx[a_g];
  }
  #pragma unroll
  for (int im = 0; im < 4; im++) {
    #pragma unroll
    for (int r = 0; r < 4; r++) {
      float rowsum = 0.f;
      #pragma unroll
      for (int in = 0; in < 4; in++)
        rowsum += fast_tanh(acc[im][in][r] + pbv[in]) * ctxv[in];
      #pragma unroll
      for (int m = 1; m < 16; m <<= 1)
        rowsum += __shfl_xor(rowsum, m, 64);
      if (l15 == 0) {
        int rowg = mtile * 128 + wm * 64 + im * 16 + g * 4 + r;
        sp[(size_t)(ntile * 2 + wn) * MROWS + rowg] = rowsum;
      }
    }
  }
}

// ---------- fused tail: softmax from 8 partials + weighted sum over s ----------
// grid (16 s-chunks, 64 batches), 256 thr (r11-proven wsum2, 8-partial input).
__global__ __launch_bounds__(256) void wsum2_kernel(
    const float* __restrict__ X, const float* __restrict__ sp,
    const void* __restrict__ lens, float* __restrict__ op)
{
  int sc = blockIdx.x;   // 0..15
  int b  = blockIdx.y;   // 0..63
  int tid = threadIdx.x;
  int s0 = sc * 128;
  int len = read_len(lens, b);
  int cnt = min(128, len - s0);
  float* o = op + ((size_t)sc * BB + b) * HH;
  if (cnt <= 0) {   // fully masked chunk: op is poisoned, must write zeros
    *(float2*)(o + tid * 2) = make_float2(0.f, 0.f);
    return;
  }

  __shared__ float redm[4], reds[4];
  __shared__ float wsh[128];
  __shared__ f32x4 red[128];

  int wv = tid >> 6, lane = tid & 63;
  float scv[8];
  float m = -1e30f;
  #pragma unroll
  for (int i = 0; i < 8; i++) {
    int s = tid + i * 256;
    size_t row = (size_t)b * SS + s;
    float v = 0.f;
    #pragma unroll
    for (int p = 0; p < 8; p++) v += sp[(size_t)p * MROWS + row];
    scv[i] = v;
    if (s < len) m = fmaxf(m, v);
  }
  #pragma unroll
  for (int off = 1; off < 64; off <<= 1) m = fmaxf(m, __shfl_xor(m, off, 64));
  if (lane == 0) redm[wv] = m;
  __syncthreads();
  m = fmaxf(fmaxf(redm[0], redm[1]), fmaxf(redm[2], redm[3]));
  float sum = 0.f;
  #pragma unroll
  for (int i = 0; i < 8; i++) {
    int s = tid + i * 256;
    sum += (s < len) ? __expf(scv[i] - m) : 0.f;
  }
  #pragma unroll
  for (int off = 1; off < 64; off <<= 1) sum += __shfl_xor(sum, off, 64);
  if (lane == 0) reds[wv] = sum;
  __syncthreads();
  float inv = 1.f / (reds[0] + reds[1] + reds[2] + reds[3]);

  if (tid < 128) {
    int s = s0 + tid;
    size_t row = (size_t)b * SS + s;
    float v = 0.f;
    #pragma unroll
    for (int p = 0; p < 8; p++) v += sp[(size_t)p * MROWS + row];
    wsh[tid] = (s < len) ? __expf(v - m) * inv : 0.f;
  }
  __syncthreads();

  // weighted column sum (r6-proven loop; X is L3-resident)
  int h = (tid & 127) * 4;
  int sr = tid >> 7;
  f32x4 acc = (f32x4)0.f;
  for (int i = sr; i < cnt; i += 2) {
    float wvv = wsh[i];
    const float* xr = X + ((size_t)b * SS + s0 + i) * HH + h;
    float4 xv = *(const float4*)xr;       // 16B coalesced
    acc[0] += wvv * xv.x;
    acc[1] += wvv * xv.y;
    acc[2] += wvv * xv.z;
    acc[3] += wvv * xv.w;
  }
  if (sr == 1) red[tid & 127] = acc;
  __syncthreads();
  if (sr == 0) {
    f32x4 r2 = red[tid];
    acc[0] += r2[0]; acc[1] += r2[1]; acc[2] += r2[2]; acc[3] += r2[3];
    *(f32x4*)(o + h) = acc;
  }
}

__global__ __launch_bounds__(512) void reduce_kernel(
    const float* __restrict__ op, float* __restrict__ out)
{
  int b = blockIdx.x;
  int h = threadIdx.x;
  float v = 0.f;
  #pragma unroll
  for (int sc = 0; sc < 16; sc++) v += op[((size_t)sc * BB + b) * HH + h];
  out[(size_t)b * HH + h] = v;
}

// ================= fallback path (ws too small) =================
__global__ __launch_bounds__(256) void scores_fb(
    const float* __restrict__ X, const void* __restrict__ lens,
    const float* __restrict__ ctx, const float* __restrict__ W,
    const float* __restrict__ pb, float* __restrict__ sp)
{
  int bid = blockIdx.x;
  int wg = (bid & 7) * 512 + (bid >> 3);
  int ntile = wg & 3;
  int mtile = wg >> 2;
  int s_start = (mtile * 128) & (SS - 1);
  int b = (mtile * 128) >> 11;
  if (s_start >= read_len(lens, b)) return;

  __shared__ unsigned short As[128 * 72];
  __shared__ unsigned short Bs[128 * 72];

  int tid = threadIdx.x;
  int lane = tid & 63;
  int w = tid >> 6;
  int wm = w >> 1, wn = w & 1;
  int l15 = lane & 15, g = lane >> 4;

  f32x4 acc[4][4];
  #pragma unroll
  for (int i = 0; i < 4; i++)
    #pragma unroll
    for (int j = 0; j < 4; j++) acc[i][j] = (f32x4)0.f;

  int srow = tid >> 4;
  int scol = (tid & 15) * 4;
  const float* Xbase = X + (size_t)(mtile * 128) * HH;
  const float* Wbase = W + (size_t)(ntile * 128) * HH;

  for (int kt = 0; kt < HH; kt += 64) {
    #pragma unroll
    for (int i = 0; i < 8; i++) {
      int row = srow + i * 16;
      float4 va = *(const float4*)(Xbase + (size_t)row * HH + kt + scol);
      unsigned int p0 = (unsigned int)f2bf(va.x) | ((unsigned int)f2bf(va.y) << 16);
      unsigned int p1 = (unsigned int)f2bf(va.z) | ((unsigned int)f2bf(va.w) << 16);
      *(uint2*)&As[row * 72 + scol] = make_uint2(p0, p1);
      float4 vb = *(const float4*)(Wbase + (size_t)row * HH + kt + scol);
      unsigned int q0 = (unsigned int)f2bf(vb.x) | ((unsigned int)f2bf(vb.y) << 16);
      unsigned int q1 = (unsigned int)f2bf(vb.z) | ((unsigned int)f2bf(vb.w) << 16);
      *(uint2*)&Bs[row * 72 + scol] = make_uint2(q0, q1);
    }
    __syncthreads();
    #pragma unroll
    for (int kk = 0; kk < 64; kk += 32) {
      short8 af[4], bfr[4];
      int ko = kk + g * 8;
      #pragma unroll
      for (int im = 0; im < 4; im++)
        af[im] = *(const short8*)&As[(wm * 64 + im * 16 + l15) * 72 + ko];
      #pragma unroll
      for (int in = 0; in < 4; in++)
        bfr[in] = *(const short8*)&Bs[(wn * 64 + in * 16 + l15) * 72 + ko];
      #pragma unroll
      for (int im = 0; im < 4; im++)
        #pragma unroll
        for (int in = 0; in < 4; in++)
          acc[im][in] = __builtin_amdgcn_mfma_f32_16x16x32_bf16(
              af[im], bfr[in], acc[im][in], 0, 0, 0);
    }
    __syncthreads();
  }

  #pragma unroll
  for (int im = 0; im < 4; im++) {
    #pragma unroll
    for (int r = 0; r < 4; r++) {
      float rowsum = 0.f;
      #pragma unroll
      for (int in = 0; in < 4; in++) {
        int a_g = ntile * 128 + wn * 64 + in * 16 + l15;
        rowsum += fast_tanh(acc[im][in][r] + pb[a_g]) * ctx[a_g];
      }
      #pragma unroll
      for (int m = 1; m < 16; m <<= 1)
        rowsum += __shfl_xor(rowsum, m, 64);
      if (l15 == 0) {
        int rowg = mtile * 128 + wm * 64 + im * 16 + g * 4 + r;
        sp[(size_t)(ntile * 2 + wn) * MROWS + rowg] = rowsum;
      }
    }
  }
}

extern "C" void kernel_launch(void* const* d_in, const int* in_sizes, int n_in,
                              void* d_out, int out_size, void* d_ws, size_t ws_size,
                              hipStream_t stream) {
  const float* X   = (const float*)d_in[0];
  const void*  lens = d_in[1];
  const float* ctx = (const float*)d_in[2];
  const float* W   = (const float*)d_in[3];
  const float* pb  = (const float*)d_in[4];
  float* out = (float*)d_out;

  char* ws = (char*)d_ws;
  const size_t WB_BYTES = (size_t)HH * HH * 2;             // 512 KB
  const size_t SP_BYTES = 8ull * MROWS * 4;                // 4 MB
  const size_t OP_BYTES = 16ull * BB * HH * 4;             // 2 MB
  const size_t NEED = WB_BYTES + SP_BYTES + OP_BYTES;

  if (ws_size >= NEED) {
    unsigned short* Wb = (unsigned short*)ws;
    float* sp = (float*)(ws + WB_BYTES);
    float* op = (float*)(ws + WB_BYTES + SP_BYTES);

    convw_kernel<<<8, 256, 0, stream>>>(W, Wb);
    scores4<<<4096, 256, 0, stream>>>(X, Wb, lens, ctx, pb, sp);
    wsum2_kernel<<<dim3(16, BB), 256, 0, stream>>>(X, sp, lens, op);
    reduce_kernel<<<BB, 512, 0, stream>>>(op, out);
  } else {
    float* sp = (float*)ws;
    float* op = (float*)(ws + SP_BYTES);

    scores_fb<<<4096, 256, 0, stream>>>(X, lens, ctx, W, pb, sp);
    wsum2_kernel<<<dim3(16, BB), 256, 0, stream>>>(X, sp, lens, op);
    reduce_kernel<<<BB, 512, 0, stream>>>(op, out);
  }
}

// Round 17
// 129.934 us; speedup vs baseline: 1.1486x; 1.1486x over previous
//
#include <hip/hip_runtime.h>

#define BB 64
#define SS 2048
#define HH 512
#define MROWS (BB*SS)  // 131072

typedef __attribute__((ext_vector_type(8))) short short8;
typedef __attribute__((ext_vector_type(4))) float f32x4;

__device__ inline unsigned short f2bf(float f){
  unsigned int u = __float_as_uint(f);
  u += 0x7FFFu + ((u >> 16) & 1u);   // RNE
  return (unsigned short)(u >> 16);
}

// batch_lens may be int64 (reference) or int32. For int64 LE the high word of
// element 0 is 0 (lens in [1,2048]); for int32, p[1] is a len >= 1.
__device__ inline int read_len(const void* lens, int i){
  const int* p = (const int*)lens;
  if (p[1] == 0) return (int)((const long long*)lens)[i];
  return p[i];
}

__device__ inline float fast_tanh(float x){
  x = fminf(fmaxf(x, -15.f), 15.f);
  float e = __expf(2.f * x);
  return (e - 1.f) / (e + 1.f);
}

__device__ inline void gload16(const void* gptr, void* lptr){
  __builtin_amdgcn_global_load_lds(
      (const __attribute__((address_space(1))) void*)gptr,
      (__attribute__((address_space(3))) void*)lptr, 16, 0, 0);
}

__device__ inline short8 cvt8p(float4 x0, float4 x1){
  short8 r;
  r[0] = (short)f2bf(x0.x); r[1] = (short)f2bf(x0.y);
  r[2] = (short)f2bf(x0.z); r[3] = (short)f2bf(x0.w);
  r[4] = (short)f2bf(x1.x); r[5] = (short)f2bf(x1.y);
  r[6] = (short)f2bf(x1.z); r[7] = (short)f2bf(x1.w);
  return r;
}

// ---------- tiny pre-convert: W only (1 MB -> 512 KB bf16) ----------
__global__ __launch_bounds__(256) void convw_kernel(
    const float* __restrict__ W, unsigned short* __restrict__ Wb)
{
  size_t base = (size_t)blockIdx.x * 64 * HH;
  int t = threadIdx.x;
  #pragma unroll
  for (int j = 0; j < 32; j++) {
    size_t idx = base + (size_t)j * 1024 + t * 4;
    float4 v = *(const float4*)(W + idx);
    unsigned int p0 = (unsigned int)f2bf(v.x) | ((unsigned int)f2bf(v.y) << 16);
    unsigned int p1 = (unsigned int)f2bf(v.z) | ((unsigned int)f2bf(v.w) << 16);
    *(uint2*)(Wb + idx) = make_uint2(p0, p1);
  }
}

// ---------- fused: r6 GEMM (verbatim) + softmax partials + LDS-PV ----------
// BM=128, BN=512, BK=64, 512 thr / 8 waves as 2M x 4N, wave tile 64x128.
// After the GEMM: per-block softmax partials (m_loc, sum e) + weighted
// column-sum over this block's 128 rows, with X re-staged chunk-wise into
// the free Bs LDS via global_load_lds (L2-hot). combine_kernel finishes.
__global__ __launch_bounds__(512, 2) void scores_fused(
    const float* __restrict__ X, const unsigned short* __restrict__ Wb,
    const void* __restrict__ lens, const float* __restrict__ ctx,
    const float* __restrict__ pb, float* __restrict__ P,
    float* __restrict__ pm, float* __restrict__ ps)
{
  int bid = blockIdx.x;
  int mtile = (bid & 7) * 128 + (bid >> 3);   // XCD swizzle (1024 % 8 == 0)
  int s_start = (mtile * 128) & (SS - 1);
  int b = (mtile * 128) >> 11;
  int len = read_len(lens, b);
  if (s_start >= len) return;
  int cnt = min(128, len - s_start);

  __shared__ __align__(16) unsigned short As[128 * 64];      // 16 KB, swz
  __shared__ __align__(16) unsigned short Bs[2][512 * 64];   // 2 x 64 KB, swz

  int tid = threadIdx.x;
  int lane = tid & 63;
  int w = tid >> 6;
  int wm = w >> 2, wn = w & 3; // 2M x 4N, wave tile 64 x 128
  int l15 = lane & 15, g = lane >> 4;

  f32x4 acc[4][8];
  #pragma unroll
  for (int i = 0; i < 4; i++)
    #pragma unroll
    for (int j = 0; j < 8; j++) acc[i][j] = (f32x4)0.f;

  int arow = tid >> 2;
  int alg0 = (tid & 3) * 2;
  const float* Ag = X + (size_t)(mtile * 128 + arow) * HH + alg0 * 8;
  int apg0 = (alg0)     ^ (arow & 7);
  int apg1 = (alg0 + 1) ^ (arow & 7);

  int brow = lane >> 3;
  int blg = (lane & 7) ^ brow;
  const unsigned short* Bg = Wb + (size_t)brow * HH + blg * 8;

  float4 ar[4];

#define A_ISSUE(KT) { const float* p_ = Ag + (KT); \
    ar[0] = *(const float4*)p_;       ar[1] = *(const float4*)(p_ + 4); \
    ar[2] = *(const float4*)(p_ + 8); ar[3] = *(const float4*)(p_ + 12); }

#define A_WRITE() { \
    *(short8*)&As[arow * 64 + apg0 * 8] = cvt8p(ar[0], ar[1]); \
    *(short8*)&As[arow * 64 + apg1 * 8] = cvt8p(ar[2], ar[3]); }

#define B_ISSUE(BUF, KT) { _Pragma("unroll") for (int i_ = 0; i_ < 8; i_++) { \
    int j_ = w * 8 + i_; \
    gload16(Bg + (size_t)(j_ * 8) * HH + (KT), &Bs[BUF][(j_ * 8) * 64]); } }

  A_ISSUE(0)
  B_ISSUE(0, 0)
  A_WRITE()
  __syncthreads();

  int cur = 0;
  for (int t = 0; t < 8; ++t) {
    if (t < 7) {
      A_ISSUE((t + 1) * 64)
      B_ISSUE(cur ^ 1, (t + 1) * 64)
    }
    #pragma unroll
    for (int kk = 0; kk < 64; kk += 32) {
      int ga = g + (kk >> 3);
      int pga = (ga ^ (l15 & 7)) * 8;
      short8 af[4];
      #pragma unroll
      for (int im = 0; im < 4; im++) {
        int r = wm * 64 + im * 16 + l15;
        af[im] = *(const short8*)&As[r * 64 + pga];
      }
      #pragma unroll
      for (int in = 0; in < 8; in++) {
        int r2 = wn * 128 + in * 16 + l15;
        short8 bfr = *(const short8*)&Bs[cur][r2 * 64 + pga];
        #pragma unroll
        for (int im = 0; im < 4; im++)
          acc[im][in] = __builtin_amdgcn_mfma_f32_16x16x32_bf16(
              af[im], bfr, acc[im][in], 0, 0, 0);
      }
    }
    __syncthreads();
    if (t < 7) A_WRITE()
    __syncthreads();
    cur ^= 1;
  }

  // ---- epilogue 1: tanh(P+pb)*ctx -> per-row score (red) ----
  float pbv[8], ctxv[8];
  #pragma unroll
  for (int in = 0; in < 8; in++) {
    int a_g = wn * 128 + in * 16 + l15;
    pbv[in] = pb[a_g];
    ctxv[in] = ctx[a_g];
  }
  float* fb  = (float*)As;        // As region reused: 4096 floats
  float* red  = fb;               // [512]
  float* esh  = fb + 512;         // [128] unnormalized exp weights
  float* wrd  = fb + 640;         // [2] max
  float* wrd2 = fb + 642;         // [2] sum
  f32x4* redp = (f32x4*)(fb + 1024);  // [256] PV reduce buffer
  #pragma unroll
  for (int im = 0; im < 4; im++) {
    #pragma unroll
    for (int r = 0; r < 4; r++) {
      float rowsum = 0.f;
      #pragma unroll
      for (int in = 0; in < 8; in++)
        rowsum += fast_tanh(acc[im][in][r] + pbv[in]) * ctxv[in];
      #pragma unroll
      for (int m = 1; m < 16; m <<= 1)
        rowsum += __shfl_xor(rowsum, m, 64);
      if (l15 == 0)
        red[wn * 128 + wm * 64 + im * 16 + g * 4 + r] = rowsum;
    }
  }
  __syncthreads();

  // ---- epilogue 2: block softmax partials (r7-verified pattern) ----
  float sc = 0.f;
  if (tid < 128)
    sc = red[tid] + red[128 + tid] + red[256 + tid] + red[384 + tid];
  float v = (tid < 128 && tid < cnt) ? sc : -1e30f;
  #pragma unroll
  for (int off = 1; off < 64; off <<= 1) v = fmaxf(v, __shfl_xor(v, off, 64));
  if (tid < 128 && (tid & 63) == 0) wrd[tid >> 6] = v;
  __syncthreads();
  float m_loc = fmaxf(wrd[0], wrd[1]);
  float e = 0.f;
  if (tid < 128) {
    e = (tid < cnt) ? __expf(sc - m_loc) : 0.f;
    esh[tid] = e;
  }
  float s1 = e;
  #pragma unroll
  for (int off = 1; off < 64; off <<= 1) s1 += __shfl_xor(s1, off, 64);
  if (tid < 128 && (tid & 63) == 0) wrd2[tid >> 6] = s1;
  __syncthreads();   // esh + wrd2 visible to all
  if (tid == 0) {
    pm[mtile] = m_loc;
    ps[mtile] = wrd2[0] + wrd2[1];
  }

  // ---- epilogue 3: PV from LDS-restaged X (L2-hot), 4 chunks of 128 cols ----
  float* BsF = (float*)Bs;        // 64 KB chunk buffer (Bs reads all done)
  int rowoff = w * 2 + (lane >> 5);      // per-lane source row within instr
  int coloff = (lane & 31) * 4;          // per-lane source col
  const float* Xb2 = X + (size_t)(mtile * 128) * HH;
  int sgrp = tid >> 5;                   // 0..15
  int h4s  = tid & 31;                   // 32 f32x4 col-slots
  for (int c = 0; c < 4; ++c) {
    #pragma unroll
    for (int i = 0; i < 8; i++) {
      gload16(Xb2 + (size_t)(i * 16 + rowoff) * HH + c * 128 + coloff,
              (char*)BsF + i * 8192 + w * 1024);
    }
    __syncthreads();   // chunk staged (drains vmcnt)
    f32x4 a4 = (f32x4)0.f;
    #pragma unroll
    for (int j = 0; j < 8; j++) {
      int s = sgrp + j * 16;
      float wv = esh[s];
      f32x4 xv = *(const f32x4*)&BsF[s * 128 + h4s * 4];
      a4[0] += wv * xv[0]; a4[1] += wv * xv[1];
      a4[2] += wv * xv[2]; a4[3] += wv * xv[3];
    }
    // pair-reduce across the two sgrps in this wave (lanes l <-> l+32)
    #pragma unroll
    for (int q = 0; q < 4; q++) a4[q] += __shfl_xor(a4[q], 32, 64);
    if (lane < 32) redp[w * 32 + lane] = a4;
    __syncthreads();
    if (tid < 32) {
      f32x4 s4 = redp[tid];
      #pragma unroll
      for (int q = 1; q < 8; q++) {
        f32x4 r4 = redp[q * 32 + tid];
        s4[0] += r4[0]; s4[1] += r4[1]; s4[2] += r4[2]; s4[3] += r4[3];
      }
      *(f32x4*)&P[(size_t)mtile * HH + c * 128 + tid * 4] = s4;
    }
  }
}

// ---------- combine: rescale 16 block-partials per batch (r7-verified) ----------
__global__ __launch_bounds__(512) void combine_kernel(
    const float* __restrict__ P, const float* __restrict__ pm,
    const float* __restrict__ ps, const void* __restrict__ lens,
    float* __restrict__ out)
{
  int b = blockIdx.x;
  int tid = threadIdx.x;
  int len = read_len(lens, b);
  int nblk = (len + 127) >> 7;
  float m = -1e30f;
  for (int k = 0; k < nblk; ++k) m = fmaxf(m, pm[b * 16 + k]);
  float S = 0.f, acc = 0.f;
  for (int k = 0; k < nblk; ++k) {
    float f = __expf(pm[b * 16 + k] - m);
    S += f * ps[b * 16 + k];
    acc += f * P[(size_t)(b * 16 + k) * HH + tid];
  }
  out[(size_t)b * HH + tid] = acc / S;
}

// ================= fallback path (ws too small) =================
__global__ __launch_bounds__(256) void scores_fb(
    const float* __restrict__ X, const void* __restrict__ lens,
    const float* __restrict__ ctx, const float* __restrict__ W,
    const float* __restrict__ pb, float* __restrict__ sp)
{
  int bid = blockIdx.x;
  int wg = (bid & 7) * 512 + (bid >> 3);
  int ntile = wg & 3;
  int mtile = wg >> 2;
  int s_start = (mtile * 128) & (SS - 1);
  int b = (mtile * 128) >> 11;
  if (s_start >= read_len(lens, b)) return;

  __shared__ unsigned short As[128 * 72];
  __shared__ unsigned short Bs[128 * 72];

  int tid = threadIdx.x;
  int lane = tid & 63;
  int w = tid >> 6;
  int wm = w >> 1, wn = w & 1;
  int l15 = lane & 15, g = lane >> 4;

  f32x4 acc[4][4];
  #pragma unroll
  for (int i = 0; i < 4; i++)
    #pragma unroll
    for (int j = 0; j < 4; j++) acc[i][j] = (f32x4)0.f;

  int srow = tid >> 4;
  int scol = (tid & 15) * 4;
  const float* Xbase = X + (size_t)(mtile * 128) * HH;
  const float* Wbase = W + (size_t)(ntile * 128) * HH;

  for (int kt = 0; kt < HH; kt += 64) {
    #pragma unroll
    for (int i = 0; i < 8; i++) {
      int row = srow + i * 16;
      float4 va = *(const float4*)(Xbase + (size_t)row * HH + kt + scol);
      unsigned int p0 = (unsigned int)f2bf(va.x) | ((unsigned int)f2bf(va.y) << 16);
      unsigned int p1 = (unsigned int)f2bf(va.z) | ((unsigned int)f2bf(va.w) << 16);
      *(uint2*)&As[row * 72 + scol] = make_uint2(p0, p1);
      float4 vb = *(const float4*)(Wbase + (size_t)row * HH + kt + scol);
      unsigned int q0 = (unsigned int)f2bf(vb.x) | ((unsigned int)f2bf(vb.y) << 16);
      unsigned int q1 = (unsigned int)f2bf(vb.z) | ((unsigned int)f2bf(vb.w) << 16);
      *(uint2*)&Bs[row * 72 + scol] = make_uint2(q0, q1);
    }
    __syncthreads();
    #pragma unroll
    for (int kk = 0; kk < 64; kk += 32) {
      short8 af[4], bfr[4];
      int ko = kk + g * 8;
      #pragma unroll
      for (int im = 0; im < 4; im++)
        af[im] = *(const short8*)&As[(wm * 64 + im * 16 + l15) * 72 + ko];
      #pragma unroll
      for (int in = 0; in < 4; in++)
        bfr[in] = *(const short8*)&Bs[(wn * 64 + in * 16 + l15) * 72 + ko];
      #pragma unroll
      for (int im = 0; im < 4; im++)
        #pragma unroll
        for (int in = 0; in < 4; in++)
          acc[im][in] = __builtin_amdgcn_mfma_f32_16x16x32_bf16(
              af[im], bfr[in], acc[im][in], 0, 0, 0);
    }
    __syncthreads();
  }

  #pragma unroll
  for (int im = 0; im < 4; im++) {
    #pragma unroll
    for (int r = 0; r < 4; r++) {
      float rowsum = 0.f;
      #pragma unroll
      for (int in = 0; in < 4; in++) {
        int a_g = ntile * 128 + wn * 64 + in * 16 + l15;
        rowsum += fast_tanh(acc[im][in][r] + pb[a_g]) * ctx[a_g];
      }
      #pragma unroll
      for (int m = 1; m < 16; m <<= 1)
        rowsum += __shfl_xor(rowsum, m, 64);
      if (l15 == 0) {
        int rowg = mtile * 128 + wm * 64 + im * 16 + g * 4 + r;
        sp[(size_t)(ntile * 2 + wn) * MROWS + rowg] = rowsum;
      }
    }
  }
}

__global__ __launch_bounds__(256) void softmax8_kernel(
    const float* __restrict__ sp, const void* __restrict__ lens,
    float* __restrict__ wts)
{
  int b = blockIdx.x;
  int tid = threadIdx.x;
  int len = read_len(lens, b);
  float sc[8];
  #pragma unroll
  for (int i = 0; i < 8; i++) {
    int s = tid + i * 256;
    size_t row = (size_t)b * SS + s;
    float v = 0.f;
    #pragma unroll
    for (int p = 0; p < 8; p++) v += sp[(size_t)p * MROWS + row];
    sc[i] = v;
  }
  float m = -1e30f;
  #pragma unroll
  for (int i = 0; i < 8; i++)
    if (tid + i * 256 < len) m = fmaxf(m, sc[i]);
  #pragma unroll
  for (int off = 1; off < 64; off <<= 1) m = fmaxf(m, __shfl_xor(m, off, 64));
  __shared__ float redm[4];
  __shared__ float reds[4];
  int w = tid >> 6, lane = tid & 63;
  if (lane == 0) redm[w] = m;
  __syncthreads();
  m = fmaxf(fmaxf(redm[0], redm[1]), fmaxf(redm[2], redm[3]));
  float e[8]; float sum = 0.f;
  #pragma unroll
  for (int i = 0; i < 8; i++) {
    int s = tid + i * 256;
    e[i] = (s < len) ? __expf(sc[i] - m) : 0.f;
    sum += e[i];
  }
  #pragma unroll
  for (int off = 1; off < 64; off <<= 1) sum += __shfl_xor(sum, off, 64);
  if (lane == 0) reds[w] = sum;
  __syncthreads();
  sum = reds[0] + reds[1] + reds[2] + reds[3];
  float inv = 1.f / sum;
  #pragma unroll
  for (int i = 0; i < 8; i++) {
    int s = tid + i * 256;
    wts[(size_t)b * SS + s] = e[i] * inv;
  }
}

__global__ __launch_bounds__(256) void wsum_fb(
    const float* __restrict__ X, const float* __restrict__ wts,
    const void* __restrict__ lens, float* __restrict__ op)
{
  int sc = blockIdx.x;
  int b  = blockIdx.y;
  int tid = threadIdx.x;
  int s0 = sc * 128;
  int len = read_len(lens, b);
  int cnt = min(128, len - s0);
  float* o = op + ((size_t)sc * BB + b) * HH;
  if (cnt <= 0) {
    *(float2*)(o + tid * 2) = make_float2(0.f, 0.f);
    return;
  }
  __shared__ float wsh[128];
  __shared__ f32x4 red[128];
  if (tid < 128) wsh[tid] = wts[(size_t)b * SS + s0 + tid];
  __syncthreads();
  int h = (tid & 127) * 4;
  int sr = tid >> 7;
  f32x4 acc = (f32x4)0.f;
  for (int i = sr; i < cnt; i += 2) {
    float wv = wsh[i];
    const float* xr = X + ((size_t)b * SS + s0 + i) * HH + h;
    float4 xv = *(const float4*)xr;
    acc[0] += wv * xv.x;
    acc[1] += wv * xv.y;
    acc[2] += wv * xv.z;
    acc[3] += wv * xv.w;
  }
  if (sr == 1) red[tid & 127] = acc;
  __syncthreads();
  if (sr == 0) {
    f32x4 r2 = red[tid];
    acc[0] += r2[0]; acc[1] += r2[1]; acc[2] += r2[2]; acc[3] += r2[3];
    *(f32x4*)(o + h) = acc;
  }
}

__global__ __launch_bounds__(512) void reduce_kernel(
    const float* __restrict__ op, float* __restrict__ out)
{
  int b = blockIdx.x;
  int h = threadIdx.x;
  float v = 0.f;
  #pragma unroll
  for (int sc = 0; sc < 16; sc++) v += op[((size_t)sc * BB + b) * HH + h];
  out[(size_t)b * HH + h] = v;
}

extern "C" void kernel_launch(void* const* d_in, const int* in_sizes, int n_in,
                              void* d_out, int out_size, void* d_ws, size_t ws_size,
                              hipStream_t stream) {
  const float* X   = (const float*)d_in[0];
  const void*  lens = d_in[1];
  const float* ctx = (const float*)d_in[2];
  const float* W   = (const float*)d_in[3];
  const float* pb  = (const float*)d_in[4];
  float* out = (float*)d_out;

  char* ws = (char*)d_ws;
  const size_t WB_BYTES = (size_t)HH * HH * 2;             // 512 KB
  const size_t P_BYTES  = 1024ull * HH * 4;                // 2 MB
  const size_t PM_BYTES = 1024 * 4;                        // 4 KB
  const size_t NEED = WB_BYTES + P_BYTES + 2 * PM_BYTES;

  if (ws_size >= NEED) {
    unsigned short* Wb = (unsigned short*)ws;
    float* P  = (float*)(ws + WB_BYTES);
    float* pm = (float*)(ws + WB_BYTES + P_BYTES);
    float* ps = (float*)(ws + WB_BYTES + P_BYTES + PM_BYTES);

    convw_kernel<<<8, 256, 0, stream>>>(W, Wb);
    scores_fused<<<1024, 512, 0, stream>>>(X, Wb, lens, ctx, pb, P, pm, ps);
    combine_kernel<<<BB, 512, 0, stream>>>(P, pm, ps, lens, out);
  } else {
    const size_t SP_BYTES = 8ull * MROWS * 4;
    const size_t WT_BYTES = (size_t)BB * SS * 4;
    float* sp  = (float*)ws;
    float* wts = (float*)(ws + SP_BYTES);
    float* op  = (float*)(ws + SP_BYTES + WT_BYTES);

    scores_fb<<<4096, 256, 0, stream>>>(X, lens, ctx, W, pb, sp);
    softmax8_kernel<<<BB, 256, 0, stream>>>(sp, lens, wts);
    wsum_fb<<<dim3(16, BB), 256, 0, stream>>>(X, wts, lens, op);
    reduce_kernel<<<BB, 512, 0, stream>>>(op, out);
  }
}